// Round 6
// baseline (521.329 us; speedup 1.0000x reference)
//
#include <hip/hip_runtime.h>

// ---------------------------------------------------------------------------
// Attention_73813307949177
//   kx = k Wk^T + bk ; qx = q Wq^T + bq
//   score = softmax2(softmax1(qx kx^T + bias)*wei + bias)
//   out = (score kx) Wp^T + bp
// Outputs (concat): out [4096,1024] fp32, score [4096,4096] fp32
//
// R5 -> R6: score GEMM is at the m97-structure plateau (42.6% MfmaUtil,
// barrier-drain bound) -- leave it. Attack tier 2:
//  * masking folded into score-GEMM epilogue (writes -1e16 sentinel);
//    softmax recovers mask via l > -1e15 -> softmax reads 235MB not 302MB
//    and the mask fetch overlaps MFMA inside the GEMM.
//  * softmax vectorized: 16 contiguous cols/thread, f32x4/bf16x8.
//  * prep kernels merged into one 5-slice launch.
// ---------------------------------------------------------------------------

typedef __bf16 bf16;
typedef __bf16 bf16x8 __attribute__((ext_vector_type(8)));
typedef __bf16 bf16x4 __attribute__((ext_vector_type(4)));
typedef float  f32x4  __attribute__((ext_vector_type(4)));
typedef float  f32x16 __attribute__((ext_vector_type(16)));

typedef __attribute__((address_space(1))) void as1_void;
typedef __attribute__((address_space(3))) void as3_void;

#define NQ  4096
#define NKK 4096
#define EMB 1024

#define BM 128
#define BN 128
#define BK 32

__device__ __forceinline__ void gld_lds16(const void* g, void* l) {
    __builtin_amdgcn_global_load_lds((as1_void*)g, (as3_void*)l, 16, 0, 0);
}

// ---------------------------------------------------------------------------
// prep: fp32 -> bf16 hi/lo split; 5 tensors batched via blockIdx.y
__global__ __launch_bounds__(256) void prep_all(
    const float* __restrict__ q, const float* __restrict__ k,
    const float* __restrict__ Wq, const float* __restrict__ Wk, const float* __restrict__ Wp,
    bf16* __restrict__ qh, bf16* __restrict__ ql,
    bf16* __restrict__ kh, bf16* __restrict__ kl,
    bf16* __restrict__ Wqh, bf16* __restrict__ Wql,
    bf16* __restrict__ Wkh, bf16* __restrict__ Wkl,
    bf16* __restrict__ Wph, bf16* __restrict__ Wpl,
    int nqk, int nw)
{
    const int z = blockIdx.y;
    const float* s; bf16* h; bf16* l; int n;
    switch (z) {
        case 0:  s = q;  h = qh;  l = ql;  n = nqk; break;
        case 1:  s = k;  h = kh;  l = kl;  n = nqk; break;
        case 2:  s = Wq; h = Wqh; l = Wql; n = nw;  break;
        case 3:  s = Wk; h = Wkh; l = Wkl; n = nw;  break;
        default: s = Wp; h = Wph; l = Wpl; n = nw;  break;
    }
    const int i = (blockIdx.x * 256 + threadIdx.x) * 4;
    if (i >= n) return;
    f32x4 v = *(const f32x4*)(s + i);
    bf16x4 hv, lv;
#pragma unroll
    for (int c = 0; c < 4; c++) {
        float x = v[c];
        bf16 hh = (bf16)x;
        hv[c] = hh;
        lv[c] = (bf16)(x - (float)hh);
    }
    *(bf16x4*)(h + i) = hv;
    *(bf16x4*)(l + i) = lv;
}

__global__ __launch_bounds__(256) void transpose_bf16(
    const bf16* __restrict__ src, bf16* __restrict__ dst, int R, int C)
{
    __shared__ bf16 tile[32][33];
    const int bx = blockIdx.x * 32;
    const int by = blockIdx.y * 32;
    const int tx = threadIdx.x & 31;
    const int ty = threadIdx.x >> 5;
#pragma unroll
    for (int r = 0; r < 4; r++)
        tile[ty + 8 * r][tx] = src[(size_t)(by + ty + 8 * r) * C + bx + tx];
    __syncthreads();
#pragma unroll
    for (int r = 0; r < 4; r++)
        dst[(size_t)(bx + ty + 8 * r) * R + by + tx] = tile[tx][ty + 8 * r];
}

// ---------------------------------------------------------------------------
template<int NS, int MODE>  // 0: sum->bf16. 1: sum+bias->f32.
__global__ __launch_bounds__(256) void reduce_k(
    const float* __restrict__ P, const float* __restrict__ bias,
    float* __restrict__ of, bf16* __restrict__ oh, int n, int Nld)
{
    const int i = (blockIdx.x * 256 + threadIdx.x) * 4;
    if (i >= n) return;
    f32x4 v = *(const f32x4*)(P + i);
#pragma unroll
    for (int s = 1; s < NS; s++)
        v += *(const f32x4*)(P + (size_t)s * n + i);
    if (MODE == 1)
        v += *(const f32x4*)(bias + (i & (Nld - 1)));
    if (MODE == 0) {
        bf16x4 o;
#pragma unroll
        for (int c = 0; c < 4; c++) o[c] = (bf16)v[c];
        *(bf16x4*)(oh + i) = o;
    } else {
        *(f32x4*)(of + i) = v;
    }
}

// ---------------------------------------------------------------------------
// Plain bf16 gemm_bt (32x32x16 core, swizzled LDS): C = A[M,K] B[N,K]^T.
template<int NSPLIT, int HAS_BIAS, int OUT_BF16>
__global__ __launch_bounds__(256) void gemm_bt(
    const bf16* __restrict__ A, const bf16* __restrict__ B,
    const float* __restrict__ bias,
    float* __restrict__ Cf, bf16* __restrict__ Cb,
    int M, int N, int Ksub, int lda, int ldb)
{
    __shared__ bf16 sA[BM * BK];
    __shared__ bf16 sB[BN * BK];
    const int t    = threadIdx.x;
    const int wave = t >> 6;
    const int lane = t & 63;
    const int l31  = lane & 31;
    const int lhi  = lane >> 5;
    const int wm   = wave >> 1;
    const int wn   = wave & 1;
    const int bm   = blockIdx.y * BM;
    const int bn   = blockIdx.x * BN;
    const int srow = t >> 2;
    const int gseg = (t & 3) ^ ((srow >> 1) & 3);
    const int rsw  = (l31 >> 1) & 3;
    const int kz   = (NSPLIT > 0) ? (int)blockIdx.z : 0;

    A += (size_t)kz * Ksub;
    B += (size_t)kz * Ksub;
    if (NSPLIT > 0) Cf += (size_t)kz * M * N;

    const bf16* ga = A + (size_t)(bm + srow) * lda + gseg * 8;
    const bf16* gb = B + (size_t)(bn + srow) * ldb + gseg * 8;
    char* lA = (char*)sA + wave * 1024;
    char* lB = (char*)sB + wave * 1024;

    f32x16 acc[2][2] = {};

    for (int k0 = 0; k0 < Ksub; k0 += BK) {
        __syncthreads();
        gld_lds16(ga + k0,                      lA);
        gld_lds16(ga + (size_t)64 * lda + k0,   lA + 4096);
        gld_lds16(gb + k0,                      lB);
        gld_lds16(gb + (size_t)64 * ldb + k0,   lB + 4096);
        __syncthreads();
        bf16x8 af[2][2], bfr[2][2];
#pragma unroll
        for (int mi = 0; mi < 2; mi++)
#pragma unroll
            for (int kh = 0; kh < 2; kh++)
                af[mi][kh] = *(const bf16x8*)
                    &sA[(wm * 64 + mi * 32 + l31) * BK + ((kh * 2 + lhi) ^ rsw) * 8];
#pragma unroll
        for (int nj = 0; nj < 2; nj++)
#pragma unroll
            for (int kh = 0; kh < 2; kh++)
                bfr[nj][kh] = *(const bf16x8*)
                    &sB[(wn * 64 + nj * 32 + l31) * BK + ((kh * 2 + lhi) ^ rsw) * 8];
#pragma unroll
        for (int kh = 0; kh < 2; kh++)
#pragma unroll
            for (int mi = 0; mi < 2; mi++)
#pragma unroll
                for (int nj = 0; nj < 2; nj++)
                    acc[mi][nj] = __builtin_amdgcn_mfma_f32_32x32x16_bf16(
                        af[mi][kh], bfr[nj][kh], acc[mi][nj], 0, 0, 0);
    }

#pragma unroll
    for (int mi = 0; mi < 2; mi++)
#pragma unroll
        for (int nj = 0; nj < 2; nj++) {
            const int cg = bn + wn * 64 + nj * 32 + l31;
            const float bv = HAS_BIAS ? bias[cg] : 0.0f;
#pragma unroll
            for (int r = 0; r < 16; r++) {
                const int rg = bm + wm * 64 + mi * 32 + (r & 3) + 8 * (r >> 2) + 4 * lhi;
                const float v = acc[mi][nj][r] + bv;
                const size_t idx = (size_t)rg * N + cg;
                if (NSPLIT > 0)    Cf[idx] = v;
                else if (OUT_BF16) Cb[idx] = (bf16)v;
                else               Cf[idx] = v;
            }
        }
}

// ---------------------------------------------------------------------------
// Split-precision gemm_bt (32x32x16, 2x2 wave tile) — projections.
template<int BATCH, int HAS_BIAS, int HILO>
__global__ __launch_bounds__(256) void gemm_bt_split(
    const bf16* __restrict__ Ah0, const bf16* __restrict__ Al0,
    const bf16* __restrict__ Bh0, const bf16* __restrict__ Bl0,
    const float* __restrict__ bias0, bf16* __restrict__ Ch0, bf16* __restrict__ Cl0,
    const bf16* __restrict__ Ah1, const bf16* __restrict__ Al1,
    const bf16* __restrict__ Bh1, const bf16* __restrict__ Bl1,
    const float* __restrict__ bias1, bf16* __restrict__ Ch1, bf16* __restrict__ Cl1,
    float* __restrict__ Cf,
    int M, int N, int K)
{
    __shared__ bf16 sAh[BM * BK], sAl[BM * BK], sBh[BN * BK], sBl[BN * BK];
    const int t    = threadIdx.x;
    const int wave = t >> 6;
    const int lane = t & 63;
    const int l31  = lane & 31;
    const int lhi  = lane >> 5;
    const int wm   = wave >> 1;
    const int wn   = wave & 1;
    const int bm   = blockIdx.y * BM;
    const int bn   = blockIdx.x * BN;
    const int srow = t >> 2;
    const int gseg = (t & 3) ^ ((srow >> 1) & 3);
    const int rsw  = (l31 >> 1) & 3;

    const int mt = BATCH ? (int)blockIdx.z : 0;

    const bf16* Ah = (BATCH && mt) ? Ah1 : Ah0;
    const bf16* Al = (BATCH && mt) ? Al1 : Al0;
    const bf16* Bh = (BATCH && mt) ? Bh1 : Bh0;
    const bf16* Bl = (BATCH && mt) ? Bl1 : Bl0;
    const float* bias = (BATCH && mt) ? bias1 : bias0;
    bf16* Ch = (BATCH && mt) ? Ch1 : Ch0;
    bf16* Cl = (BATCH && mt) ? Cl1 : Cl0;

    const size_t offA = (size_t)(bm + srow) * K + gseg * 8;
    const size_t offB = (size_t)(bn + srow) * K + gseg * 8;
    char* lAh = (char*)sAh + wave * 1024;
    char* lAl = (char*)sAl + wave * 1024;
    char* lBh = (char*)sBh + wave * 1024;
    char* lBl = (char*)sBl + wave * 1024;

    f32x16 acc[2][2] = {};

    for (int k0 = 0; k0 < K; k0 += BK) {
        __syncthreads();
        gld_lds16(Ah + offA + k0,                  lAh);
        gld_lds16(Ah + offA + (size_t)64 * K + k0, lAh + 4096);
        gld_lds16(Al + offA + k0,                  lAl);
        gld_lds16(Al + offA + (size_t)64 * K + k0, lAl + 4096);
        gld_lds16(Bh + offB + k0,                  lBh);
        gld_lds16(Bh + offB + (size_t)64 * K + k0, lBh + 4096);
        gld_lds16(Bl + offB + k0,                  lBl);
        gld_lds16(Bl + offB + (size_t)64 * K + k0, lBl + 4096);
        __syncthreads();
#pragma unroll
        for (int kh = 0; kh < 2; kh++) {
            const int ksw = ((kh * 2 + lhi) ^ rsw) * 8;
            bf16x8 ah[2], al[2], bh2[2], bl2[2];
#pragma unroll
            for (int mi = 0; mi < 2; mi++) {
                const int ro = (wm * 64 + mi * 32 + l31) * BK + ksw;
                ah[mi] = *(const bf16x8*)&sAh[ro];
                al[mi] = *(const bf16x8*)&sAl[ro];
            }
#pragma unroll
            for (int nj = 0; nj < 2; nj++) {
                const int ro = (wn * 64 + nj * 32 + l31) * BK + ksw;
                bh2[nj] = *(const bf16x8*)&sBh[ro];
                bl2[nj] = *(const bf16x8*)&sBl[ro];
            }
#pragma unroll
            for (int mi = 0; mi < 2; mi++)
#pragma unroll
                for (int nj = 0; nj < 2; nj++) {
                    acc[mi][nj] = __builtin_amdgcn_mfma_f32_32x32x16_bf16(al[mi], bh2[nj], acc[mi][nj], 0, 0, 0);
                    acc[mi][nj] = __builtin_amdgcn_mfma_f32_32x32x16_bf16(ah[mi], bl2[nj], acc[mi][nj], 0, 0, 0);
                    acc[mi][nj] = __builtin_amdgcn_mfma_f32_32x32x16_bf16(ah[mi], bh2[nj], acc[mi][nj], 0, 0, 0);
                }
        }
    }

#pragma unroll
    for (int mi = 0; mi < 2; mi++)
#pragma unroll
        for (int nj = 0; nj < 2; nj++) {
            const int cg = bn + wn * 64 + nj * 32 + l31;
            const float bv = HAS_BIAS ? bias[cg] : 0.0f;
#pragma unroll
            for (int r = 0; r < 16; r++) {
                const int rg = bm + wm * 64 + mi * 32 + (r & 3) + 8 * (r >> 2) + 4 * lhi;
                const float v = acc[mi][nj][r] + bv;
                const size_t idx = (size_t)rg * N + cg;
                if (HILO) {
                    const bf16 hh = (bf16)v;
                    Ch[idx] = hh;
                    Cl[idx] = (bf16)(v - (float)hh);
                } else {
                    Cf[idx] = v;
                }
            }
        }
}

// ---------------------------------------------------------------------------
// Score GEMM: split precision, 4x2 wave tile (wave = 128x64), block 128x256.
// Epilogue folds the mask: writes -1e16 sentinel where mask==0 (matches the
// reference's additive bias exactly for softmax purposes).
__global__ __launch_bounds__(256, 2) void gemm_score(
    const bf16* __restrict__ Ah, const bf16* __restrict__ Al,
    const bf16* __restrict__ Bh, const bf16* __restrict__ Bl,
    const int* __restrict__ mask,
    float* __restrict__ Cf, int N, int K)
{
    __shared__ bf16 sAh[128 * BK], sAl[128 * BK], sBh[256 * BK], sBl[256 * BK];
    const int t    = threadIdx.x;
    const int wave = t >> 6;
    const int lane = t & 63;
    const int l31  = lane & 31;
    const int lhi  = lane >> 5;
    const int bm   = blockIdx.y * 128;
    const int bn   = blockIdx.x * 256;
    const int srow = t >> 2;
    const int gseg = (t & 3) ^ ((srow >> 1) & 3);
    const int rsw  = (l31 >> 1) & 3;

    const size_t offA = (size_t)(bm + srow) * K + gseg * 8;
    const size_t offB = (size_t)(bn + srow) * K + gseg * 8;
    char* lAh = (char*)sAh + wave * 1024;
    char* lAl = (char*)sAl + wave * 1024;
    char* lBh = (char*)sBh + wave * 1024;
    char* lBl = (char*)sBl + wave * 1024;

    f32x16 acc[4][2] = {};

    for (int k0 = 0; k0 < K; k0 += BK) {
        __syncthreads();
        gld_lds16(Ah + offA + k0,                  lAh);
        gld_lds16(Ah + offA + (size_t)64 * K + k0, lAh + 4096);
        gld_lds16(Al + offA + k0,                  lAl);
        gld_lds16(Al + offA + (size_t)64 * K + k0, lAl + 4096);
#pragma unroll
        for (int rb = 0; rb < 4; rb++) {
            gld_lds16(Bh + offB + (size_t)(64 * rb) * K + k0, lBh + rb * 4096);
            gld_lds16(Bl + offB + (size_t)(64 * rb) * K + k0, lBl + rb * 4096);
        }
        __syncthreads();
#pragma unroll
        for (int kh = 0; kh < 2; kh++) {
            const int ksw = ((kh * 2 + lhi) ^ rsw) * 8;
            bf16x8 ah[4], al[4], bh2[2], bl2[2];
#pragma unroll
            for (int mi = 0; mi < 4; mi++) {
                const int ro = (mi * 32 + l31) * BK + ksw;
                ah[mi] = *(const bf16x8*)&sAh[ro];
                al[mi] = *(const bf16x8*)&sAl[ro];
            }
#pragma unroll
            for (int nj = 0; nj < 2; nj++) {
                const int ro = (wave * 64 + nj * 32 + l31) * BK + ksw;
                bh2[nj] = *(const bf16x8*)&sBh[ro];
                bl2[nj] = *(const bf16x8*)&sBl[ro];
            }
#pragma unroll
            for (int mi = 0; mi < 4; mi++)
#pragma unroll
                for (int nj = 0; nj < 2; nj++) {
                    acc[mi][nj] = __builtin_amdgcn_mfma_f32_32x32x16_bf16(al[mi], bh2[nj], acc[mi][nj], 0, 0, 0);
                    acc[mi][nj] = __builtin_amdgcn_mfma_f32_32x32x16_bf16(ah[mi], bl2[nj], acc[mi][nj], 0, 0, 0);
                    acc[mi][nj] = __builtin_amdgcn_mfma_f32_32x32x16_bf16(ah[mi], bh2[nj], acc[mi][nj], 0, 0, 0);
                }
        }
    }

#pragma unroll
    for (int mi = 0; mi < 4; mi++)
#pragma unroll
        for (int nj = 0; nj < 2; nj++) {
            const int cg = bn + wave * 64 + nj * 32 + l31;
#pragma unroll
            for (int r = 0; r < 16; r++) {
                const int rg = bm + mi * 32 + (r & 3) + 8 * (r >> 2) + 4 * lhi;
                const size_t idx = (size_t)rg * N + cg;
                Cf[idx] = mask[idx] ? acc[mi][nj][r] : -1e16f;
            }
        }
}

// ---------------------------------------------------------------------------
__device__ __forceinline__ float wred_max(float v) {
#pragma unroll
    for (int off = 32; off > 0; off >>= 1) v = fmaxf(v, __shfl_xor(v, off));
    return v;
}
__device__ __forceinline__ float wred_sum(float v) {
#pragma unroll
    for (int off = 32; off > 0; off >>= 1) v += __shfl_xor(v, off);
    return v;
}

// Fused double softmax; mask recovered from -1e16 sentinel (logits are
// O(100), sentinel is -1e16 -> threshold -1e15 is unambiguous).
// Vectorized: thread t owns 16 contiguous cols.
__global__ __launch_bounds__(256) void softmax2_kernel(
    float* __restrict__ score, const float* __restrict__ wei,
    bf16* __restrict__ scoreb)
{
    __shared__ float sred[4];
    const int row = blockIdx.x;
    const int t   = threadIdx.x;
    const size_t base = (size_t)row * NKK + (size_t)t * 16;
    const int wv = t >> 6, ln = t & 63;

    float l[16], w[16];
#pragma unroll
    for (int c = 0; c < 4; c++) {
        *(f32x4*)(l + 4 * c) = *(const f32x4*)(score + base + 4 * c);
        *(f32x4*)(w + 4 * c) = *(const f32x4*)(wei + base + 4 * c);
    }
    unsigned mb = 0;
#pragma unroll
    for (int s = 0; s < 16; s++) if (l[s] > -1e15f) mb |= 1u << s;

    // pass 1
    float mx = -__builtin_inff();
#pragma unroll
    for (int s = 0; s < 16; s++) if (mb & (1u << s)) mx = fmaxf(mx, l[s]);
    mx = wred_max(mx);
    if (ln == 0) sred[wv] = mx;
    __syncthreads();
    mx = fmaxf(fmaxf(sred[0], sred[1]), fmaxf(sred[2], sred[3]));
    __syncthreads();
    float sum = 0.f;
#pragma unroll
    for (int s = 0; s < 16; s++) {
        const float e = (mb & (1u << s)) ? __expf(l[s] - mx) : 0.f;
        l[s] = e; sum += e;
    }
    sum = wred_sum(sum);
    if (ln == 0) sred[wv] = sum;
    __syncthreads();
    sum = sred[0] + sred[1] + sred[2] + sred[3];
    __syncthreads();
    const float inv1 = 1.0f / sum;

#pragma unroll
    for (int s = 0; s < 16; s++) l[s] = l[s] * inv1 * w[s];

    // pass 2
    float mx2 = -__builtin_inff();
#pragma unroll
    for (int s = 0; s < 16; s++) if (mb & (1u << s)) mx2 = fmaxf(mx2, l[s]);
    mx2 = wred_max(mx2);
    if (ln == 0) sred[wv] = mx2;
    __syncthreads();
    mx2 = fmaxf(fmaxf(sred[0], sred[1]), fmaxf(sred[2], sred[3]));
    __syncthreads();
    float sum2 = 0.f;
#pragma unroll
    for (int s = 0; s < 16; s++) {
        const float e = (mb & (1u << s)) ? __expf(l[s] - mx2) : 0.f;
        l[s] = e; sum2 += e;
    }
    sum2 = wred_sum(sum2);
    if (ln == 0) sred[wv] = sum2;
    __syncthreads();
    sum2 = sred[0] + sred[1] + sred[2] + sred[3];
    const float inv2 = 1.0f / sum2;

#pragma unroll
    for (int c = 0; c < 4; c++) {
        f32x4 pv;
#pragma unroll
        for (int j = 0; j < 4; j++) pv[j] = l[4 * c + j] * inv2;
        *(f32x4*)(score + base + 4 * c) = pv;
#pragma unroll
        for (int j = 0; j < 4; j++) l[4 * c + j] = pv[j];
    }
    bf16x8 b0, b1;
#pragma unroll
    for (int j = 0; j < 8; j++) { b0[j] = (bf16)l[j]; b1[j] = (bf16)l[8 + j]; }
    *(bf16x8*)(scoreb + base)     = b0;
    *(bf16x8*)(scoreb + base + 8) = b1;
}

// ---------------------------------------------------------------------------
extern "C" void kernel_launch(void* const* d_in, const int* in_sizes, int n_in,
                              void* d_out, int out_size, void* d_ws, size_t ws_size,
                              hipStream_t stream)
{
    (void)in_sizes; (void)n_in; (void)out_size;
    const float* q    = (const float*)d_in[0];
    const float* k    = (const float*)d_in[1];
    const int*   mask = (const int*)  d_in[2];
    const float* wei  = (const float*)d_in[3];
    const float* Wq   = (const float*)d_in[4];
    const float* bq   = (const float*)d_in[5];
    const float* Wk   = (const float*)d_in[6];
    const float* bk   = (const float*)d_in[7];
    const float* Wp   = (const float*)d_in[8];
    const float* bp   = (const float*)d_in[9];

    float* out   = (float*)d_out;
    float* score = (float*)d_out + (size_t)NQ * EMB;

    char* ws = (char*)d_ws;
    size_t off = 0;
    auto alloc = [&](size_t bytes) -> char* {
        char* p = ws + off; off += (bytes + 255) & ~(size_t)255; return p;
    };
    const size_t n_qk = (size_t)NQ * EMB;
    const size_t n_w  = (size_t)EMB * EMB;
    const size_t n_sc = (size_t)NQ * NKK;

    bf16* qh   = (bf16*)alloc(n_qk * 2);
    bf16* ql   = (bf16*)alloc(n_qk * 2);
    bf16* kh   = (bf16*)alloc(n_qk * 2);
    bf16* kl   = (bf16*)alloc(n_qk * 2);
    bf16* qxh  = (bf16*)alloc(n_qk * 2);
    bf16* qxl  = (bf16*)alloc(n_qk * 2);
    bf16* kxh  = (bf16*)alloc(n_qk * 2);
    bf16* kxl  = (bf16*)alloc(n_qk * 2);
    bf16* Wqh  = (bf16*)alloc(n_w * 2);
    bf16* Wql  = (bf16*)alloc(n_w * 2);
    bf16* Wkh  = (bf16*)alloc(n_w * 2);
    bf16* Wkl  = (bf16*)alloc(n_w * 2);
    bf16* Wpb  = (bf16*)alloc(n_w * 2);
    bf16* Wpl  = (bf16*)alloc(n_w * 2);
    bf16* kxTb = (bf16*)alloc(n_qk * 2);
    bf16* ctxb = (bf16*)alloc(n_qk * 2);
    bf16* scoreb = (bf16*)alloc(n_sc * 2);
    const size_t base_off = off;
    float* P = (float*)alloc(2 * n_qk * 4);
    const bool ws_ok = (off <= ws_size);
    if (base_off > ws_size) return;

    const int MN = (int)n_qk;

    // 1) prep: all 5 hi/lo splits in one launch
    prep_all<<<dim3(n_qk / 1024, 5), 256, 0, stream>>>(
        q, k, Wq, Wk, Wp,
        qh, ql, kh, kl, Wqh, Wql, Wkh, Wkl, Wpb, Wpl,
        (int)n_qk, (int)n_w);

    // 2) projections: batched z=2, direct bias + hi/lo epilogue
    gemm_bt_split<1, 1, 1><<<dim3(EMB / BN, NQ / BM, 2), 256, 0, stream>>>(
        qh, ql, Wqh, Wql, bq, qxh, qxl,
        kh, kl, Wkh, Wkl, bk, kxh, kxl,
        nullptr, NQ, EMB, EMB);

    // 3) kx^T for ctx GEMM B-operand
    transpose_bf16<<<dim3(EMB / 32, NKK / 32), 256, 0, stream>>>(kxh, kxTb, NKK, EMB);

    // 4) score logits = qx kx^T, masked epilogue (-1e16 sentinel)
    gemm_score<<<dim3(NKK / 256, NQ / 128), 256, 0, stream>>>(
        qxh, qxl, kxh, kxl, mask, score, NKK, EMB);

    // 5) fused double softmax (mask from sentinel; vectorized)
    softmax2_kernel<<<dim3(NQ), 256, 0, stream>>>(score, wei, scoreb);

    // 6) ctx = p2 @ kx  (split-K=2)
    if (ws_ok) {
        gemm_bt<2, 0, 0><<<dim3(EMB / BN, NQ / BM, 2), 256, 0, stream>>>(
            scoreb, kxTb, nullptr, P, nullptr, NQ, EMB, NKK / 2, NKK, NKK);
        reduce_k<2, 0><<<dim3(MN / 1024), 256, 0, stream>>>(
            P, nullptr, nullptr, ctxb, MN, EMB);
    } else {
        gemm_bt<0, 0, 1><<<dim3(EMB / BN, NQ / BM), 256, 0, stream>>>(
            scoreb, kxTb, nullptr, nullptr, ctxb, NQ, EMB, NKK, NKK, NKK);
    }

    // 7) out = ctx @ Wp^T + bp  (split-K=2)
    if (ws_ok) {
        gemm_bt<2, 0, 0><<<dim3(EMB / BN, NQ / BM, 2), 256, 0, stream>>>(
            ctxb, Wpb, nullptr, P, nullptr, NQ, EMB, EMB / 2, EMB, EMB);
        reduce_k<2, 1><<<dim3(MN / 1024), 256, 0, stream>>>(
            P, bp, out, nullptr, MN, EMB);
    } else {
        gemm_bt<0, 1, 0><<<dim3(EMB / BN, NQ / BM), 256, 0, stream>>>(
            ctxb, Wpb, bp, out, nullptr, NQ, EMB, EMB, EMB, EMB);
    }
}